// Round 20
// baseline (32.117 us; speedup 1.0000x reference)
//
#include <hip/hip_runtime.h>

namespace {

constexpr int B = 4;
constexpr int M = 128;
constexpr int ITP = 10;
constexpr int P = M * ITP;            // 1280 queries per batch
constexpr int NPTS = 20000;
constexpr int NQ = B * P;             // 5120 queries
constexpr int QPW = 8;                // queries per wave
constexpr int WPB = 4;                // waves per block -> 32 queries/block
constexpr int QPB = QPW * WPB;        // 32
constexpr int NCHUNKS = 8;
constexpr int CHUNK = NPTS / NCHUNKS; // 2500
constexpr int GX = NQ / QPB;          // 160 blocks in x; grid 160x8=1280 (5/CU, 1 round)
constexpr int FULL_ITERS = CHUNK / 64;            // 39
constexpr int TAIL = CHUNK - FULL_ITERS * 64;     // 4
constexpr int C4 = CHUNK * 3 / 4;     // 1875 float4 per chunk (30000 B)
constexpr float EPSF = 0.01f;

// t = linspace(0,1,10): nearest-f32 of j/9
__device__ const float T_TAB[ITP] = {0.0f,
    (float)(1.0 / 9.0), (float)(2.0 / 9.0), (float)(3.0 / 9.0),
    (float)(4.0 / 9.0), (float)(5.0 / 9.0), (float)(6.0 / 9.0),
    (float)(7.0 / 9.0), (float)(8.0 / 9.0), 1.0f};

// Interpolated cage point, replicating reference rounding (mul,mul,add; no fma)
__device__ __forceinline__ void query_point(const float* __restrict__ cage,
                                            int b, int p,
                                            float& x, float& y, float& z) {
  const int m = p / ITP;
  const int j = p - m * ITP;
  const float t = T_TAB[j];
  const float omt = __fsub_rn(1.0f, t);
  const float* c0 = cage + ((size_t)b * M + m) * 3;
  const float* c1 = cage + ((size_t)b * M + ((m + 1) & (M - 1))) * 3;
  x = __fadd_rn(__fmul_rn(t, c1[0]), __fmul_rn(omt, c0[0]));
  y = __fadd_rn(__fmul_rn(t, c1[1]), __fmul_rn(omt, c0[1]));
  z = __fadd_rn(__fmul_rn(t, c1[2]), __fmul_rn(omt, c0[2]));
}

// Kernel 1: LDS-staged argmin scan (R15 numerics, unchanged). ONE delta vs
// R15: the LDS reads are software-pipelined — iter t+1's point is prefetched
// into registers while iter t computes, making load-use distance one full
// iteration (~124 cyc compute >= ~120 cyc LDS latency) instead of an
// unroll-group boundary lgkmcnt stall.
__global__ __launch_bounds__(256) void k_nn_lds(
    const float* __restrict__ cage,
    const float* __restrict__ shape,
    unsigned long long* __restrict__ part) {
  __shared__ float4 smem4[C4];            // 30000 B chunk stage

  const int tid  = threadIdx.x;
  const int lane = tid & 63;
  const int wid  = tid >> 6;
  const int bx   = blockIdx.x;            // query group (32 queries)
  const int ck   = blockIdx.y;            // chunk
  const int q0   = bx * QPB + wid * QPW;
  const int b    = (bx * QPB) / P;        // uniform per block (32 | 1280)
  const int p0   = q0 - b * P;

  // ---- stage chunk into LDS (float4 x 1875) ----
  const float4* g4 = reinterpret_cast<const float4*>(shape + (size_t)b * NPTS * 3)
                     + (size_t)ck * C4;
  for (int i = tid; i < C4; i += 256) smem4[i] = g4[i];

  // ---- per-wave query setup (overlaps staging latency) ----
  float cx[QPW], cy[QPW], cz[QPW];
#pragma unroll
  for (int i = 0; i < QPW; ++i) {
    float x, y, z;
    query_point(cage, b, p0 + i, x, y, z);
    cx[i] = x; cy[i] = y; cz[i] = z;
  }
  float minv[QPW];
  unsigned int mini[QPW];
#pragma unroll
  for (int i = 0; i < QPW; ++i) { minv[i] = __int_as_float(0x7f800000); mini[i] = 0u; }

  __syncthreads();
  const float* sm = reinterpret_cast<const float*>(smem4);
  const int nbase = ck * CHUNK;

  // ---- scan loop: software-pipelined LDS reads (prefetch t+1, compute t) ----
  int jl = lane;
  float px = sm[3 * jl], py = sm[3 * jl + 1], pz = sm[3 * jl + 2];

  // iters 0..FULL_ITERS-2 (38): prefetch j+64 always in-bounds (<= 2495)
#pragma unroll 4
  for (int it = 0; it < FULL_ITERS - 1; ++it) {
    const int jn = jl + 64;
    const float fx = sm[3 * jn], fy = sm[3 * jn + 1], fz = sm[3 * jn + 2];
    const float ss = __fadd_rn(__fadd_rn(__fmul_rn(px, px), __fmul_rn(py, py)),
                               __fmul_rn(pz, pz));
    const int n = nbase + jl;
#pragma unroll
    for (int i = 0; i < QPW; ++i) {
      const float dot = __fmaf_rn(cz[i], pz, __fmaf_rn(cy[i], py, __fmul_rn(cx[i], px)));
      const float key = __fmaf_rn(-2.0f, dot, ss);   // argmin key (cc dropped, R15)
      if (key < minv[i]) { minv[i] = key; mini[i] = (unsigned int)n; }  // strict <
    }
    px = fx; py = fy; pz = fz; jl = jn;
  }
  {  // it = FULL_ITERS-1: compute current, prefetch tail iter (masked addr)
    const int jt = (lane < TAIL) ? (jl + 64) : lane;   // tail lanes; others dummy
    const float fx = sm[3 * jt], fy = sm[3 * jt + 1], fz = sm[3 * jt + 2];
    const float ss = __fadd_rn(__fadd_rn(__fmul_rn(px, px), __fmul_rn(py, py)),
                               __fmul_rn(pz, pz));
    const int n = nbase + jl;
#pragma unroll
    for (int i = 0; i < QPW; ++i) {
      const float dot = __fmaf_rn(cz[i], pz, __fmaf_rn(cy[i], py, __fmul_rn(cx[i], px)));
      const float key = __fmaf_rn(-2.0f, dot, ss);
      if (key < minv[i]) { minv[i] = key; mini[i] = (unsigned int)n; }
    }
    px = fx; py = fy; pz = fz; jl = (lane < TAIL) ? (jl + 64) : lane;
  }
  {  // tail iter: only lanes < TAIL valid; mask via ss=+inf (key=+inf never wins)
    float ss = __fadd_rn(__fadd_rn(__fmul_rn(px, px), __fmul_rn(py, py)),
                         __fmul_rn(pz, pz));
    if (lane >= TAIL) ss = __int_as_float(0x7f800000);
    const int n = nbase + jl;
#pragma unroll
    for (int i = 0; i < QPW; ++i) {
      const float dot = __fmaf_rn(cz[i], pz, __fmaf_rn(cy[i], py, __fmul_rn(cx[i], px)));
      const float key = __fmaf_rn(-2.0f, dot, ss);
      if (key < minv[i]) { minv[i] = key; mini[i] = (unsigned int)n; }
    }
  }

  // ---- per-wave argmin reduce, write packed partials ----
#pragma unroll
  for (int i = 0; i < QPW; ++i) {
    unsigned int fb = __float_as_uint(minv[i]);
    fb = (fb & 0x80000000u) ? ~fb : (fb | 0x80000000u);  // monotone total order
    unsigned long long pk = ((unsigned long long)fb << 32) | (unsigned long long)mini[i];
#pragma unroll
    for (int s = 32; s >= 1; s >>= 1) {
      const unsigned long long o = __shfl_xor(pk, s, 64);
      pk = (o < pk) ? o : pk;   // equal key -> smaller idx (first-index tie-break)
    }
    if (lane == i) part[(size_t)(q0 + i) * NCHUNKS + ck] = pk;
  }
}

// Kernel 2: one thread per query: merge chunk partials (chunk-index order),
// compute loss term with the EXACT reference formula, fixed-order tree-reduce.
__global__ __launch_bounds__(256) void k_loss(
    const float* __restrict__ cage,
    const float* __restrict__ shape,
    const float* __restrict__ normals,
    const unsigned long long* __restrict__ part,
    float* __restrict__ blocksum) {
  const int tid = threadIdx.x;
  const int q = blockIdx.x * 256 + tid;   // NQ = 20 blocks * 256

  unsigned long long best = ~0ull;
#pragma unroll
  for (int c = 0; c < NCHUNKS; ++c) {
    const unsigned long long v = part[(size_t)q * NCHUNKS + c];
    if (v < best) best = v;   // strict < in ascending chunk order keeps first index
  }
  const int idx = (int)(best & 0xffffffffu);
  const int b = q / P;
  const int p = q - b * P;
  float qx, qy, qz;
  query_point(cage, b, p, qx, qy, qz);
  const float* sp = shape   + ((size_t)b * NPTS + idx) * 3;
  const float* sn = normals + ((size_t)b * NPTS + idx) * 3;
  const float nx = sn[0], ny = sn[1], nz = sn[2];
  const float vx = __fsub_rn(__fsub_rn(qx, sp[0]), __fmul_rn(EPSF, nx));
  const float vy = __fsub_rn(__fsub_rn(qy, sp[1]), __fmul_rn(EPSF, ny));
  const float vz = __fsub_rn(__fsub_rn(qz, sp[2]), __fmul_rn(EPSF, nz));
  const float dot = __fadd_rn(__fadd_rn(__fmul_rn(vx, nx), __fmul_rn(vy, ny)),
                              __fmul_rn(vz, nz));
  const float loss = (dot < 0.0f) ? -dot : 0.0f;

  __shared__ float red[256];
  red[tid] = loss;
  __syncthreads();
#pragma unroll
  for (int s = 128; s >= 1; s >>= 1) {
    if (tid < s) red[tid] = __fadd_rn(red[tid], red[tid + s]);
    __syncthreads();
  }
  if (tid == 0) blocksum[blockIdx.x] = red[0];
}

// Kernel 3: sum the 20 block partials (single wave, fixed butterfly order).
__global__ __launch_bounds__(64) void k_sum(const float* __restrict__ blocksum,
                                            float* __restrict__ out) {
  const int lane = threadIdx.x;
  float v = (lane < NQ / 256) ? blocksum[lane] : 0.0f;
#pragma unroll
  for (int s = 32; s >= 1; s >>= 1) v = __fadd_rn(v, __shfl_xor(v, s, 64));
  if (lane == 0) out[0] = v / (float)NQ;
}

}  // namespace

extern "C" void kernel_launch(void* const* d_in, const int* in_sizes, int n_in,
                              void* d_out, int out_size, void* d_ws, size_t ws_size,
                              hipStream_t stream) {
  (void)in_sizes; (void)n_in; (void)out_size; (void)ws_size;
  const float* cage    = (const float*)d_in[0];
  const float* shape   = (const float*)d_in[1];
  const float* normals = (const float*)d_in[2];
  float* out = (float*)d_out;

  char* ws = (char*)d_ws;
  unsigned long long* part = (unsigned long long*)ws;        // 5120*8*8B = 320 KB
  float* blocksum = (float*)(ws + 320 * 1024);               // 20 floats

  dim3 grid1(GX, NCHUNKS);   // 160 x 8 = 1280 blocks (5/CU, one round), 4 waves
  k_nn_lds<<<grid1, 256, 0, stream>>>(cage, shape, part);
  k_loss<<<NQ / 256, 256, 0, stream>>>(cage, shape, normals, part, blocksum);
  k_sum<<<1, 64, 0, stream>>>(blocksum, out);
}

// Round 21
// 31.118 us; speedup vs baseline: 1.0321x; 1.0321x over previous
//
#include <hip/hip_runtime.h>

namespace {

constexpr int B = 4;
constexpr int M = 128;
constexpr int ITP = 10;
constexpr int P = M * ITP;            // 1280 queries per batch
constexpr int NPTS = 20000;
constexpr int NQ = B * P;             // 5120 queries
constexpr int QPW = 8;                // queries per wave
constexpr int WPB = 4;                // waves per block -> 32 queries/block
constexpr int QPB = QPW * WPB;        // 32
constexpr int NCHUNKS = 8;
constexpr int CHUNK = NPTS / NCHUNKS; // 2500
constexpr int GX = NQ / QPB;          // 160 blocks in x; grid 160x8=1280 (5/CU, 1 round)
constexpr int FULL_ITERS = CHUNK / 64;            // 39
constexpr int TAIL = CHUNK - FULL_ITERS * 64;     // 4
constexpr int C4 = CHUNK * 3 / 4;     // 1875 float4 per chunk (30000 B)
constexpr float EPSF = 0.01f;

// t = linspace(0,1,10): nearest-f32 of j/9
__device__ const float T_TAB[ITP] = {0.0f,
    (float)(1.0 / 9.0), (float)(2.0 / 9.0), (float)(3.0 / 9.0),
    (float)(4.0 / 9.0), (float)(5.0 / 9.0), (float)(6.0 / 9.0),
    (float)(7.0 / 9.0), (float)(8.0 / 9.0), 1.0f};

// Interpolated cage point, replicating reference rounding (mul,mul,add; no fma)
__device__ __forceinline__ void query_point(const float* __restrict__ cage,
                                            int b, int p,
                                            float& x, float& y, float& z) {
  const int m = p / ITP;
  const int j = p - m * ITP;
  const float t = T_TAB[j];
  const float omt = __fsub_rn(1.0f, t);
  const float* c0 = cage + ((size_t)b * M + m) * 3;
  const float* c1 = cage + ((size_t)b * M + ((m + 1) & (M - 1))) * 3;
  x = __fadd_rn(__fmul_rn(t, c1[0]), __fmul_rn(omt, c0[0]));
  y = __fadd_rn(__fmul_rn(t, c1[1]), __fmul_rn(omt, c0[1]));
  z = __fadd_rn(__fmul_rn(t, c1[2]), __fmul_rn(omt, c0[2]));
}

// Kernel 1: LDS-staged argmin scan (R15 loop structure — pipelining was
// measured neutral in R20). TWO op-count deltas vs R15:
//  (a) -2 folded into query constants (cx2=-2*cx, exact): key is a pure
//      3-fmaf chain seeded with ss -> the standalone v_mul disappears.
//  (b) mini stores chunk-local j; uniform nbase added once in the epilogue.
// Key ranks n within one query only (same formula for all n) -> argmin
// identical up to near-ties (same accepted class as R15, measured absmax 0.0).
__global__ __launch_bounds__(256) void k_nn_lds(
    const float* __restrict__ cage,
    const float* __restrict__ shape,
    unsigned long long* __restrict__ part) {
  __shared__ float4 smem4[C4];            // 30000 B chunk stage

  const int tid  = threadIdx.x;
  const int lane = tid & 63;
  const int wid  = tid >> 6;
  const int bx   = blockIdx.x;            // query group (32 queries)
  const int ck   = blockIdx.y;            // chunk
  const int q0   = bx * QPB + wid * QPW;
  const int b    = (bx * QPB) / P;        // uniform per block (32 | 1280)
  const int p0   = q0 - b * P;

  // ---- stage chunk into LDS (float4 x 1875) ----
  const float4* g4 = reinterpret_cast<const float4*>(shape + (size_t)b * NPTS * 3)
                     + (size_t)ck * C4;
  for (int i = tid; i < C4; i += 256) smem4[i] = g4[i];

  // ---- per-wave query setup: c2 = -2*c (exact scale/negate) ----
  float cx2[QPW], cy2[QPW], cz2[QPW];
#pragma unroll
  for (int i = 0; i < QPW; ++i) {
    float x, y, z;
    query_point(cage, b, p0 + i, x, y, z);
    cx2[i] = __fmul_rn(-2.0f, x);
    cy2[i] = __fmul_rn(-2.0f, y);
    cz2[i] = __fmul_rn(-2.0f, z);
  }
  float minv[QPW];
  unsigned int mini[QPW];
#pragma unroll
  for (int i = 0; i < QPW; ++i) { minv[i] = __int_as_float(0x7f800000); mini[i] = 0u; }

  __syncthreads();
  const float* sm = reinterpret_cast<const float*>(smem4);
  const int nbase = ck * CHUNK;

  // ---- scan loop: 6 VALU/pair (3 fmaf + cmp + 2 cndmask), ss amortized ----
#pragma unroll 4
  for (int it = 0; it < FULL_ITERS; ++it) {
    const int j = it * 64 + lane;
    const float px = sm[3 * j], py = sm[3 * j + 1], pz = sm[3 * j + 2];
    const float ss = __fadd_rn(__fadd_rn(__fmul_rn(px, px), __fmul_rn(py, py)),
                               __fmul_rn(pz, pz));
#pragma unroll
    for (int i = 0; i < QPW; ++i) {
      const float key = __fmaf_rn(cz2[i], pz,
                          __fmaf_rn(cy2[i], py,
                            __fmaf_rn(cx2[i], px, ss)));
      if (key < minv[i]) { minv[i] = key; mini[i] = (unsigned int)j; }  // strict <
    }
  }
  {  // tail: 4 valid lanes; others read in-bounds dummy and mask via +inf
    const int j = (lane < TAIL) ? (FULL_ITERS * 64 + lane) : lane;
    const float px = sm[3 * j], py = sm[3 * j + 1], pz = sm[3 * j + 2];
    float ss = __fadd_rn(__fadd_rn(__fmul_rn(px, px), __fmul_rn(py, py)),
                         __fmul_rn(pz, pz));
    if (lane >= TAIL) ss = __int_as_float(0x7f800000);
#pragma unroll
    for (int i = 0; i < QPW; ++i) {
      const float key = __fmaf_rn(cz2[i], pz,
                          __fmaf_rn(cy2[i], py,
                            __fmaf_rn(cx2[i], px, ss)));
      if (key < minv[i]) { minv[i] = key; mini[i] = (unsigned int)j; }
    }
  }

  // ---- per-wave argmin reduce, write packed partials (global idx = nbase+j) ----
#pragma unroll
  for (int i = 0; i < QPW; ++i) {
    unsigned int fb = __float_as_uint(minv[i]);
    fb = (fb & 0x80000000u) ? ~fb : (fb | 0x80000000u);  // monotone total order
    unsigned long long pk = ((unsigned long long)fb << 32)
                          | (unsigned long long)(mini[i] + (unsigned int)nbase);
#pragma unroll
    for (int s = 32; s >= 1; s >>= 1) {
      const unsigned long long o = __shfl_xor(pk, s, 64);
      pk = (o < pk) ? o : pk;   // equal key -> smaller idx (first-index tie-break)
    }
    if (lane == i) part[(size_t)(q0 + i) * NCHUNKS + ck] = pk;
  }
}

// Kernel 2: one thread per query: merge chunk partials (chunk-index order),
// compute loss term with the EXACT reference formula, fixed-order tree-reduce.
__global__ __launch_bounds__(256) void k_loss(
    const float* __restrict__ cage,
    const float* __restrict__ shape,
    const float* __restrict__ normals,
    const unsigned long long* __restrict__ part,
    float* __restrict__ blocksum) {
  const int tid = threadIdx.x;
  const int q = blockIdx.x * 256 + tid;   // NQ = 20 blocks * 256

  unsigned long long best = ~0ull;
#pragma unroll
  for (int c = 0; c < NCHUNKS; ++c) {
    const unsigned long long v = part[(size_t)q * NCHUNKS + c];
    if (v < best) best = v;   // strict < in ascending chunk order keeps first index
  }
  const int idx = (int)(best & 0xffffffffu);
  const int b = q / P;
  const int p = q - b * P;
  float qx, qy, qz;
  query_point(cage, b, p, qx, qy, qz);
  const float* sp = shape   + ((size_t)b * NPTS + idx) * 3;
  const float* sn = normals + ((size_t)b * NPTS + idx) * 3;
  const float nx = sn[0], ny = sn[1], nz = sn[2];
  const float vx = __fsub_rn(__fsub_rn(qx, sp[0]), __fmul_rn(EPSF, nx));
  const float vy = __fsub_rn(__fsub_rn(qy, sp[1]), __fmul_rn(EPSF, ny));
  const float vz = __fsub_rn(__fsub_rn(qz, sp[2]), __fmul_rn(EPSF, nz));
  const float dot = __fadd_rn(__fadd_rn(__fmul_rn(vx, nx), __fmul_rn(vy, ny)),
                              __fmul_rn(vz, nz));
  const float loss = (dot < 0.0f) ? -dot : 0.0f;

  __shared__ float red[256];
  red[tid] = loss;
  __syncthreads();
#pragma unroll
  for (int s = 128; s >= 1; s >>= 1) {
    if (tid < s) red[tid] = __fadd_rn(red[tid], red[tid + s]);
    __syncthreads();
  }
  if (tid == 0) blocksum[blockIdx.x] = red[0];
}

// Kernel 3: sum the 20 block partials (single wave, fixed butterfly order).
__global__ __launch_bounds__(64) void k_sum(const float* __restrict__ blocksum,
                                            float* __restrict__ out) {
  const int lane = threadIdx.x;
  float v = (lane < NQ / 256) ? blocksum[lane] : 0.0f;
#pragma unroll
  for (int s = 32; s >= 1; s >>= 1) v = __fadd_rn(v, __shfl_xor(v, s, 64));
  if (lane == 0) out[0] = v / (float)NQ;
}

}  // namespace

extern "C" void kernel_launch(void* const* d_in, const int* in_sizes, int n_in,
                              void* d_out, int out_size, void* d_ws, size_t ws_size,
                              hipStream_t stream) {
  (void)in_sizes; (void)n_in; (void)out_size; (void)ws_size;
  const float* cage    = (const float*)d_in[0];
  const float* shape   = (const float*)d_in[1];
  const float* normals = (const float*)d_in[2];
  float* out = (float*)d_out;

  char* ws = (char*)d_ws;
  unsigned long long* part = (unsigned long long*)ws;        // 5120*8*8B = 320 KB
  float* blocksum = (float*)(ws + 320 * 1024);               // 20 floats

  dim3 grid1(GX, NCHUNKS);   // 160 x 8 = 1280 blocks (5/CU, one round), 4 waves
  k_nn_lds<<<grid1, 256, 0, stream>>>(cage, shape, part);
  k_loss<<<NQ / 256, 256, 0, stream>>>(cage, shape, normals, part, blocksum);
  k_sum<<<1, 64, 0, stream>>>(blocksum, out);
}